// Round 7
// baseline (342.959 us; speedup 1.0000x reference)
//
#include <hip/hip_runtime.h>

// (B,N,D,K) = (32, 2048, 512, 256)
#define CB 32
#define CN 2048
#define CD 512
#define CK 256

typedef __bf16 bf16x8 __attribute__((ext_vector_type(8)));
typedef float  f32x4  __attribute__((ext_vector_type(4)));

__device__ __forceinline__ unsigned pk2bf(float a, float b) {   // RNE pack: 2 f32 -> bf16x2
    union { float f; unsigned u; } x, y; x.f = a; y.f = b;
    unsigned ru = x.u + 0x7fffu + ((x.u >> 16) & 1u);
    unsigned rv = y.u + 0x7fffu + ((y.u >> 16) & 1u);
    return (ru >> 16) | (rv & 0xffff0000u);
}

// ---------------- K0: vQp (blocks 0..31) + WiT (blocks 32..287) ----------------
__global__ __launch_bounds__(256) void prep_kernel(
        const float* __restrict__ vQ, const float* __restrict__ Wq,
        const float* __restrict__ bq, const float* __restrict__ Wi,
        float* __restrict__ vQp, unsigned short* __restrict__ WiT)
{
    const int tid = threadIdx.x;
    if (blockIdx.x < CB) {
        const int b = blockIdx.x;
        __shared__ float sq[CD];
        sq[tid]       = vQ[b * CD + tid];
        sq[tid + 256] = vQ[b * CD + tid + 256];
        __syncthreads();
        float acc = bq[tid];
        #pragma unroll 8
        for (int d = 0; d < CD; ++d) acc += sq[d] * Wq[d * CK + tid];
        vQp[b * CK + tid] = acc;
    } else {
        const int k = blockIdx.x - CB;
        for (int d = tid; d < CD; d += 256) {
            union { float f; unsigned u; } x; x.f = Wi[(size_t)d * CK + k];
            unsigned r = x.u + 0x7fffu + ((x.u >> 16) & 1u);
            WiT[(size_t)k * CD + d] = (unsigned short)(r >> 16);
        }
    }
}

// ---------------- K1: wave-autonomous fused scores + softmax pieces + num ----------
// Block = 128 thr (2 waves), 32 rows. Wave w computes k-half [w*128, w*128+128).
// A: global->register MFMA fragments (no LDS staging, no K-loop barriers).
// B: global->register from L2-hot WiT. Both reg-double-buffered.
// Wave 0 keeps a bf16 LDS copy of A for the num epilogue.
// grid (64, 32) = 2048 blocks.
__global__ __launch_bounds__(128, 2) void scores_fused_kernel(
        const float* __restrict__ vI, const unsigned short* __restrict__ WiT,
        const float* __restrict__ vQp, const float* __restrict__ Wp,
        float* __restrict__ numP, float* __restrict__ Zp, float* __restrict__ mP)
{
    __shared__ __align__(16) unsigned short sAl[32 * CD];   // 32 KB bf16 A copy
    __shared__ float sred[2][32];
    __shared__ float sS[32];
    __shared__ float sW[32];

    const int tid  = threadIdx.x;
    const int w    = tid >> 6;        // wave id = k-half
    const int lane = tid & 63;
    const int col  = lane & 15;       // A-row / B-row / C-col index
    const int quad = lane >> 4;       // d-group / C row-group
    const int b    = blockIdx.y;
    const int n0   = blockIdx.x * 32;
    const float* vIb = vI + ((size_t)b * CN + n0) * CD;

    // A fragment sources (rows col and 16+col), d-offset quad*8 within chunk
    const float* aS0 = vIb + (size_t)col * CD + quad * 8;
    const float* aS1 = vIb + (size_t)(16 + col) * CD + quad * 8;
    // B fragment source: WiT row w*128 + kt*16 + col
    const unsigned short* wBb = WiT + (size_t)(w * 128 + col) * CD + quad * 8;

    f32x4 acc[2][8];
    #pragma unroll
    for (int mt = 0; mt < 2; ++mt)
        #pragma unroll
        for (int kt = 0; kt < 8; ++kt)
            acc[mt][kt] = (f32x4){0.f, 0.f, 0.f, 0.f};

    // ---- prologue: loads for chunk 0 ----
    float4 Ar[4]; uint4 Bc[8];
    Ar[0] = *reinterpret_cast<const float4*>(aS0);
    Ar[1] = *reinterpret_cast<const float4*>(aS0 + 4);
    Ar[2] = *reinterpret_cast<const float4*>(aS1);
    Ar[3] = *reinterpret_cast<const float4*>(aS1 + 4);
    #pragma unroll
    for (int kt = 0; kt < 8; ++kt)
        Bc[kt] = *reinterpret_cast<const uint4*>(wBb + (size_t)kt * 16 * CD);

    // ---- K loop: 16 chunks of 32 d, NO barriers ----
    #pragma unroll
    for (int ch = 0; ch < 16; ++ch) {
        // convert current A to fragments
        uint4 af0, af1;
        af0.x = pk2bf(Ar[0].x, Ar[0].y); af0.y = pk2bf(Ar[0].z, Ar[0].w);
        af0.z = pk2bf(Ar[1].x, Ar[1].y); af0.w = pk2bf(Ar[1].z, Ar[1].w);
        af1.x = pk2bf(Ar[2].x, Ar[2].y); af1.y = pk2bf(Ar[2].z, Ar[2].w);
        af1.z = pk2bf(Ar[3].x, Ar[3].y); af1.w = pk2bf(Ar[3].z, Ar[3].w);

        // wave 0 keeps the bf16 copy for the num epilogue (swizzled 16B slots)
        if (w == 0) {
            int s0 = (ch * 4 + quad) ^ (col & 7);
            int s1 = (ch * 4 + quad) ^ ((16 + col) & 7);
            *reinterpret_cast<uint4*>(&sAl[col * CD + s0 * 8])        = af0;
            *reinterpret_cast<uint4*>(&sAl[(16 + col) * CD + s1 * 8]) = af1;
        }

        // issue next chunk's loads (in flight across the MFMAs below)
        float4 An[4]; uint4 Bn[8];
        if (ch < 15) {
            const int d0n = (ch + 1) * 32;
            An[0] = *reinterpret_cast<const float4*>(aS0 + d0n);
            An[1] = *reinterpret_cast<const float4*>(aS0 + d0n + 4);
            An[2] = *reinterpret_cast<const float4*>(aS1 + d0n);
            An[3] = *reinterpret_cast<const float4*>(aS1 + d0n + 4);
            #pragma unroll
            for (int kt = 0; kt < 8; ++kt)
                Bn[kt] = *reinterpret_cast<const uint4*>(
                    wBb + (size_t)kt * 16 * CD + d0n);
        }

        #pragma unroll
        for (int kt = 0; kt < 8; ++kt) {
            acc[0][kt] = __builtin_amdgcn_mfma_f32_16x16x32_bf16(
                __builtin_bit_cast(bf16x8, af0), __builtin_bit_cast(bf16x8, Bc[kt]),
                acc[0][kt], 0, 0, 0);
            acc[1][kt] = __builtin_amdgcn_mfma_f32_16x16x32_bf16(
                __builtin_bit_cast(bf16x8, af1), __builtin_bit_cast(bf16x8, Bc[kt]),
                acc[1][kt], 0, 0, 0);
        }
        if (ch < 15) {
            #pragma unroll
            for (int i = 0; i < 4; ++i) Ar[i] = An[i];
            #pragma unroll
            for (int kt = 0; kt < 8; ++kt) Bc[kt] = Bn[kt];
        }
    }

    // ---- epilogue 1: per-row scores (wave-local over its k-half) ----
    float vq[8], wp[8];
    #pragma unroll
    for (int kt = 0; kt < 8; ++kt) {
        int k = w * 128 + kt * 16 + col;
        vq[kt] = vQp[b * CK + k];
        wp[kt] = Wp[k];
    }
    float sp[2][4];
    #pragma unroll
    for (int mt = 0; mt < 2; ++mt)
        #pragma unroll
        for (int r = 0; r < 4; ++r) {
            float s = 0.f;
            #pragma unroll
            for (int kt = 0; kt < 8; ++kt) {
                float v = acc[mt][kt][r] + vq[kt];
                v = v > 0.f ? v : 0.01f * v;     // leaky relu
                s += v * wp[kt];
            }
            sp[mt][r] = s;
        }
    #pragma unroll
    for (int off = 1; off < 16; off <<= 1)
        #pragma unroll
        for (int mt = 0; mt < 2; ++mt)
            #pragma unroll
            for (int r = 0; r < 4; ++r)
                sp[mt][r] += __shfl_xor(sp[mt][r], off);
    if (col == 0) {
        #pragma unroll
        for (int mt = 0; mt < 2; ++mt)
            #pragma unroll
            for (int r = 0; r < 4; ++r)
                sred[w][mt * 16 + quad * 4 + r] = sp[mt][r];
    }
    __syncthreads();
    if (tid < 32) sS[tid] = sred[0][tid] + sred[1][tid];
    __syncthreads();

    // ---- epilogue 2: block-local softmax pieces (32 rows) ----
    float m = -1e30f;
    #pragma unroll 8
    for (int i = 0; i < 32; ++i) m = fmaxf(m, sS[i]);
    if (tid < 32) sW[tid] = __expf(sS[tid] - m);
    __syncthreads();
    const int pidx = b * 64 + blockIdx.x;
    if (tid == 0) {
        float z = 0.f;
        #pragma unroll
        for (int i = 0; i < 32; ++i) z += sW[i];
        Zp[pidx] = z;
        mP[pidx] = m;
    }

    // ---- epilogue 3: num[d] = sum_n w_n * A_bf16[n][d] from LDS ----
    // thread owns d-cols tid*4 .. tid*4+3
    const int slot = tid >> 1;             // 16B slot id of d-base
    const int half = (tid & 1) * 4;        // ushort offset within slot
    float a4[4] = {0.f, 0.f, 0.f, 0.f};
    #pragma unroll 8
    for (int n = 0; n < 32; ++n) {
        float w_ = sW[n];
        uint2 q = *reinterpret_cast<const uint2*>(
            &sAl[n * CD + ((slot ^ (n & 7)) << 3) + half]);
        a4[0] += w_ * __uint_as_float(q.x << 16);
        a4[1] += w_ * __uint_as_float(q.x & 0xffff0000u);
        a4[2] += w_ * __uint_as_float(q.y << 16);
        a4[3] += w_ * __uint_as_float(q.y & 0xffff0000u);
    }
    *reinterpret_cast<float4*>(&numP[(size_t)pidx * CD + tid * 4]) =
        (float4){a4[0], a4[1], a4[2], a4[3]};
}

// ---------------- K2: combine 64 partials -> vbar; out = vbar@Wi + vQp ----------------
__global__ __launch_bounds__(256) void finalize_kernel(
        const float* __restrict__ numP, const float* __restrict__ Zp,
        const float* __restrict__ mP, const float* __restrict__ Wi,
        const float* __restrict__ vQp, float* __restrict__ out)
{
    const int b = blockIdx.x, tid = threadIdx.x;
    __shared__ float sm_[64], sz[64], swj[64], sv[CD];
    if (tid < 64) {
        sm_[tid] = mP[b * 64 + tid];
        sz[tid]  = Zp[b * 64 + tid];
    }
    __syncthreads();
    float M = -1e30f;
    #pragma unroll
    for (int j = 0; j < 64; ++j) M = fmaxf(M, sm_[j]);
    if (tid < 64) swj[tid] = __expf(sm_[tid] - M);
    __syncthreads();
    float Zt = 0.f;
    #pragma unroll
    for (int j = 0; j < 64; ++j) Zt += swj[j] * sz[j];
    const float inv = 1.f / Zt;
    for (int c = tid; c < CD; c += 256) {
        float s = 0.f;
        #pragma unroll
        for (int j = 0; j < 64; ++j) s += swj[j] * numP[(size_t)(b * 64 + j) * CD + c];
        sv[c] = s * inv;
    }
    __syncthreads();
    float acc = vQp[b * CK + tid];
    #pragma unroll 8
    for (int d = 0; d < CD; ++d) acc += sv[d] * Wi[d * CK + tid];
    out[b * CK + tid] = acc;
}

extern "C" void kernel_launch(void* const* d_in, const int* in_sizes, int n_in,
                              void* d_out, int out_size, void* d_ws, size_t ws_size,
                              hipStream_t stream)
{
    const float* vI = (const float*)d_in[0];   // [B,N,D]
    const float* vQ = (const float*)d_in[1];   // [B,D]
    const float* Wi = (const float*)d_in[2];   // [D,K]
    const float* Wq = (const float*)d_in[3];   // [D,K]
    const float* bq = (const float*)d_in[4];   // [K]
    const float* Wp = (const float*)d_in[5];   // [K,1]
    // d_in[6] = bp: softmax-invariant, unused
    float* out = (float*)d_out;                // [B,K]

    char* ws = (char*)d_ws;
    float*          vQp  = (float*)(ws);                         //  32 KB
    unsigned short* WiT  = (unsigned short*)(ws + 32768);        // 256 KB
    float*          numP = (float*)(ws + 294912);                //   4 MB (2048x512)
    float*          Zp   = (float*)(ws + 294912 + 4194304);      //   8 KB
    float*          mP   = (float*)(ws + 294912 + 4194304 + 8192);

    prep_kernel        <<<CB + CK, 256, 0, stream>>>(vQ, Wq, bq, Wi, vQp, WiT);
    scores_fused_kernel<<<dim3(CN / 32, CB), 128, 0, stream>>>(vI, WiT, vQp, Wp,
                                                               numP, Zp, mP);
    finalize_kernel    <<<CB, 256, 0, stream>>>(numP, Zp, mP, Wi, vQp, out);
}